// Round 1
// baseline (2817.561 us; speedup 1.0000x reference)
//
#include <hip/hip_runtime.h>

// ---------------- workspace layout (float/int indices into d_ws) ----------
#define WS_A0 0              // commitment sum (0.5 * sum (zf - zq)^2)
#define WS_A1 1              // sum of E_dist over (n,c)
#define WS_A2 2              // sum of neg_ent over (n,c)
#define WS_QBAR 16           // 8192 floats: sum_n q[n,c,k]
#define WS_CBSQ (WS_QBAR + 8192)   // 8192 floats: ||cb[c,k]||^2
#define WS_IDX  (WS_CBSQ + 8192)   // 32768 ints: argmin index per (n,c)

// ---------------- output layout (floats) ----------------------------------
#define OUT_IDX  1048576     // indices (B,C,H,W) as float
#define OUT_Q    1081344     // q (N,C,K)
#define OUT_SCAL 34635776    // commitment, free_energy, confidence, balance, tau

__global__ __launch_bounds__(256) void k_cbsq(const float* __restrict__ cb,
                                              float* __restrict__ ws_f) {
  int i = blockIdx.x * 256 + threadIdx.x;   // 0..8191  (= c*1024 + k)
  const float* r = cb + (size_t)i * 32;
  float s = 0.f;
#pragma unroll
  for (int d = 0; d < 32; ++d) s = fmaf(r[d], r[d], s);
  ws_f[WS_CBSQ + i] = s;
}

__device__ __forceinline__ float wsum64(float v) {
#pragma unroll
  for (int m = 32; m >= 1; m >>= 1) v += __shfl_xor(v, m, 64);
  return v;
}

// main: 256 blocks (8 c x 32 n-blocks), 512 threads (8 waves), 132KB dyn LDS
__global__ __launch_bounds__(512, 2) void k_main(
    const float* __restrict__ z, const float* __restrict__ cb,
    float* __restrict__ out, float* __restrict__ ws_f, int* __restrict__ ws_i) {
  extern __shared__ float smem[];
  float* cb_lds = smem;            // 32768 floats, xor-swizzled float4 quads
  float* qsum   = smem + 32768;    // 1024 floats: per-block sum_n q

  const int c    = blockIdx.x >> 5;
  const int nblk = blockIdx.x & 31;
  const int tid  = threadIdx.x;
  const int lane = tid & 63;
  const int wave = tid >> 6;

  // ---- stage full channel codebook into LDS, quad-xor swizzle -------------
  const float4* cb4 = (const float4*)(cb + (size_t)c * 32768);
  float4* lds4 = (float4*)cb_lds;
#pragma unroll
  for (int i = 0; i < 16; ++i) {
    int idx = i * 512 + tid;            // float4 index 0..8191
    int k = idx >> 3, q = idx & 7;
    lds4[(k << 3) + (q ^ (k & 7))] = cb4[idx];
  }
  for (int i = tid; i < 1024; i += 512) qsum[i] = 0.f;
  __syncthreads();

  const float* cbsqp = ws_f + WS_CBSQ + c * 1024;
  float* out_q   = out + OUT_Q;
  float* out_idx = out + OUT_IDX;

  float accA0 = 0.f, accA1 = 0.f, accA2 = 0.f;
  const int kl7 = lane & 7;

  for (int p = 0; p < 8; ++p) {         // each wave: 8 pairs of n = 16 n
    const int nA = nblk * 128 + wave * 16 + p * 2;
    const int b  = nA >> 10;
    const int hw = nA & 1023;
    const float* zp = z + (((size_t)b * 256 + c * 32) << 10) + hw;

    float zA[32], zB[32];
#pragma unroll
    for (int d = 0; d < 32; ++d) { zA[d] = zp[d * 1024]; zB[d] = zp[d * 1024 + 1]; }
    float zsA = 0.f, zsB = 0.f;
#pragma unroll
    for (int d = 0; d < 32; ++d) { zsA = fmaf(zA[d], zA[d], zsA); zsB = fmaf(zB[d], zB[d], zsB); }

    float eA[16], eB[16];
    float zqA[32], zqB[32];
#pragma unroll
    for (int d = 0; d < 32; ++d) { zqA[d] = 0.f; zqB[d] = 0.f; }
    float SA = 0.f, SB = 0.f, esA = 0.f, esB = 0.f;
    float smA = -INFINITY, smB = -INFINITY;
    int kmA = 0, kmB = 0;

#pragma unroll
    for (int jj = 0; jj < 16; ++jj) {   // k = jj*64 + lane, covers K=1024
      const int k = jj * 64 + lane;
      float cq = cbsqp[k];
      float row[32];
#pragma unroll
      for (int q = 0; q < 8; ++q) {
        float4 r4 = lds4[(k << 3) + (q ^ kl7)];
        row[q * 4 + 0] = r4.x; row[q * 4 + 1] = r4.y;
        row[q * 4 + 2] = r4.z; row[q * 4 + 3] = r4.w;
      }
      float ca0 = 0.f, ca1 = 0.f, cb0 = 0.f, cb1 = 0.f;
#pragma unroll
      for (int d = 0; d < 32; d += 2) {
        ca0 = fmaf(row[d],     zA[d],     ca0);
        ca1 = fmaf(row[d + 1], zA[d + 1], ca1);
        cb0 = fmaf(row[d],     zB[d],     cb0);
        cb1 = fmaf(row[d + 1], zB[d + 1], cb1);
      }
      float sA = (ca0 + ca1) - 0.5f * cq;   // logits + const(n); dist = zsq - 2s
      float sB = (cb0 + cb1) - 0.5f * cq;
      float ea = __expf(sA), eb = __expf(sB);
      eA[jj] = ea; eB[jj] = eb;
      SA += ea; SB += eb;
      esA = fmaf(ea, sA, esA); esB = fmaf(eb, sB, esB);
      if (sA > smA) { smA = sA; kmA = k; }
      if (sB > smB) { smB = sB; kmB = k; }
#pragma unroll
      for (int d = 0; d < 32; ++d) {
        zqA[d] = fmaf(ea, row[d], zqA[d]);
        zqB[d] = fmaf(eb, row[d], zqB[d]);
      }
    }

    float SAt = wsum64(SA), SBt = wsum64(SB);
    float rSA = 1.f / SAt, rSB = 1.f / SBt;

    // ---- pass 2: normalized q writes + entropy + q_bar --------------------
    float neA = 0.f, neB = 0.f;
    float* qpA = out_q + ((size_t)nA * 8 + c) * 1024;
    float* qpB = qpA + 8192;
#pragma unroll
    for (int jj = 0; jj < 16; ++jj) {
      const int k = jj * 64 + lane;
      float qa = eA[jj] * rSA, qb = eB[jj] * rSB;
      __builtin_nontemporal_store(qa, qpA + k);
      __builtin_nontemporal_store(qb, qpB + k);
      atomicAdd(&qsum[k], qa + qb);
      neA = fmaf(qa, __logf(qa + 1e-8f), neA);
      neB = fmaf(qb, __logf(qb + 1e-8f), neB);
    }

    float esAt = wsum64(esA), esBt = wsum64(esB);
    float neAt = wsum64(neA), neBt = wsum64(neB);
    accA1 += (zsA - 2.f * esAt * rSA) + (zsB - 2.f * esBt * rSB); // E_dist
    accA2 += neAt + neBt;

    // ---- argmax(s) == argmin(dist), tie -> lower k -------------------------
#pragma unroll
    for (int m = 32; m >= 1; m >>= 1) {
      float soA = __shfl_xor(smA, m, 64); int koA = __shfl_xor(kmA, m, 64);
      if (soA > smA || (soA == smA && koA < kmA)) { smA = soA; kmA = koA; }
      float soB = __shfl_xor(smB, m, 64); int koB = __shfl_xor(kmB, m, 64);
      if (soB > smB || (soB == smB && koB < kmB)) { smB = soB; kmB = koB; }
    }
    if (lane == 0) {
      out_idx[(size_t)b * 8192 + c * 1024 + hw]     = (float)kmA;
      out_idx[(size_t)b * 8192 + c * 1024 + hw + 1] = (float)kmB;
      ws_i[WS_IDX + nA * 8 + c]       = kmA;
      ws_i[WS_IDX + (nA + 1) * 8 + c] = kmB;
    }

    // ---- split-butterfly reduce zq over 64 lanes; lane -> dd=(lane>>1)&31 --
#pragma unroll
    for (int t = 0; t < 5; ++t) {
      const int half = 16 >> t;
      const int up = (lane >> (5 - t)) & 1;
#pragma unroll
      for (int i = 0; i < half; ++i) {
        float sa = up ? zqA[i] : zqA[i + half];
        float ka = up ? zqA[i + half] : zqA[i];
        float sb = up ? zqB[i] : zqB[i + half];
        float kb = up ? zqB[i + half] : zqB[i];
        zqA[i] = ka + __shfl_xor(sa, 32 >> t, 64);
        zqB[i] = kb + __shfl_xor(sb, 32 >> t, 64);
      }
    }
    zqA[0] += __shfl_xor(zqA[0], 1, 64);
    zqB[0] += __shfl_xor(zqB[0], 1, 64);
    const int ddl = (lane >> 1) & 31;
    float zfa = zp[ddl * 1024], zfb = zp[ddl * 1024 + 1];
    float da = zfa - zqA[0] * rSA;
    float db = zfb - zqB[0] * rSB;
    accA0 += 0.5f * wsum64(fmaf(da, da, db * db));  // each dd counted twice
  }

  if (lane == 0) {
    atomicAdd(&ws_f[WS_A0], accA0);
    atomicAdd(&ws_f[WS_A1], accA1);
    atomicAdd(&ws_f[WS_A2], accA2);
  }
  __syncthreads();
  for (int k = tid; k < 1024; k += 512)
    atomicAdd(&ws_f[WS_QBAR + c * 1024 + k], qsum[k]);
}

// hard-quantized gather: coalesced writes of cb[c, idx[n,c], dd]
__global__ __launch_bounds__(256) void k_hard(const float* __restrict__ cb,
                                              const int* __restrict__ ws_i,
                                              float* __restrict__ out0) {
  int o = blockIdx.x * 256 + threadIdx.x;    // (b, ch, hw) row-major
  int b  = o >> 18;
  int r  = o & 262143;
  int ch = r >> 10;
  int hw = r & 1023;
  int c = ch >> 5, dd = ch & 31;
  int n = (b << 10) + hw;
  int k = ws_i[WS_IDX + n * 8 + c];
  out0[o] = cb[((size_t)(c << 10) + k) * 32 + dd];
}

__global__ __launch_bounds__(256) void k_final(const float* __restrict__ ws_f,
                                               float* __restrict__ out_s) {
  __shared__ float red[256];
  int tid = threadIdx.x;
  float bal = 0.f;
  for (int i = tid; i < 8192; i += 256) {
    float qb = ws_f[WS_QBAR + i] * (1.0f / 4096.0f);
    bal += qb * __logf(qb * 1024.0f + 1e-8f);
  }
  red[tid] = bal;
  __syncthreads();
  for (int s = 128; s > 0; s >>= 1) {
    if (tid < s) red[tid] += red[tid + s];
    __syncthreads();
  }
  if (tid == 0) {
    float A0 = ws_f[WS_A0], A1 = ws_f[WS_A1], A2 = ws_f[WS_A2];
    out_s[0] = A0 * (1.0f / 1048576.0f);                              // commitment
    out_s[1] = (0.5f * A1 + A2) * (1.0f / 32768.0f) + 6.93147180559945f; // free_energy
    out_s[2] = -A2 * (1.0f / 32768.0f);                               // confidence
    out_s[3] = red[0] * 0.125f;                                       // balance
    out_s[4] = 1.0f;                                                  // tau
  }
}

extern "C" void kernel_launch(void* const* d_in, const int* in_sizes, int n_in,
                              void* d_out, int out_size, void* d_ws, size_t ws_size,
                              hipStream_t stream) {
  (void)in_sizes; (void)n_in; (void)out_size; (void)ws_size;
  const float* z  = (const float*)d_in[0];
  const float* cb = (const float*)d_in[1];
  float* out  = (float*)d_out;
  float* ws_f = (float*)d_ws;
  int*   ws_i = (int*)d_ws;

  // 132KB dynamic LDS (> 64KB default): opt in every call (idempotent, cheap)
  hipFuncSetAttribute(reinterpret_cast<const void*>(k_main),
                      hipFuncAttributeMaxDynamicSharedMemorySize, 135168);

  hipMemsetAsync(d_ws, 0, (WS_QBAR + 8192) * sizeof(float), stream);
  k_cbsq <<<32,   256, 0,      stream>>>(cb, ws_f);
  k_main <<<256,  512, 135168, stream>>>(z, cb, out, ws_f, ws_i);
  k_hard <<<4096, 256, 0,      stream>>>(cb, ws_i, out);
  k_final<<<1,    256, 0,      stream>>>(ws_f, out + OUT_SCAL);
}

// Round 2
// 2077.145 us; speedup vs baseline: 1.3565x; 1.3565x over previous
//
#include <hip/hip_runtime.h>

// ---------------- workspace layout (float/int indices into d_ws) ----------
#define WS_A0 0              // commitment sum
#define WS_A1 1              // sum of E_dist over (n,c)
#define WS_A2 2              // sum of neg_ent over (n,c)
#define WS_QBAR 16           // 8192 floats: sum_n q[n,c,k]
#define WS_CBSQ (WS_QBAR + 8192)   // 8192 floats: ||cb[c,k]||^2
#define WS_IDX  (WS_CBSQ + 8192)   // 32768 ints: argmin index per (n,c)

// ---------------- output layout (floats) ----------------------------------
#define OUT_IDX  1048576     // indices (B,C,H,W) as float
#define OUT_Q    1081344     // q (N,C,K)
#define OUT_SCAL 34635776    // commitment, free_energy, confidence, balance, tau

__global__ __launch_bounds__(256) void k_cbsq(const float* __restrict__ cb,
                                              float* __restrict__ ws_f) {
  int i = blockIdx.x * 256 + threadIdx.x;   // 0..8191  (= c*1024 + k)
  const float* r = cb + (size_t)i * 32;
  float s = 0.f;
#pragma unroll
  for (int d = 0; d < 32; ++d) s = fmaf(r[d], r[d], s);
  ws_f[WS_CBSQ + i] = s;
}

__device__ __forceinline__ float wsum64(float v) {
#pragma unroll
  for (int m = 32; m >= 1; m >>= 1) v += __shfl_xor(v, m, 64);
  return v;
}

// main: 256 blocks (8 c x 32 n-blocks), 512 threads (8 waves), 132KB dyn LDS.
// LDS (132KB) forces 1 block/CU, so launch_bounds(512,1): 2 waves/EU -> 256 VGPR
// budget. R1's (512,2) capped VGPRs at 128 -> 2.9GB scratch spill.
__global__ __launch_bounds__(512, 1) void k_main(
    const float* __restrict__ z, const float* __restrict__ cb,
    float* __restrict__ out, float* __restrict__ ws_f, int* __restrict__ ws_i) {
  extern __shared__ float smem[];
  float* cb_lds = smem;            // 32768 floats, xor-swizzled float4 quads
  float* qsum   = smem + 32768;    // 1024 floats: per-block sum_n q

  const int c    = blockIdx.x >> 5;
  const int nblk = blockIdx.x & 31;
  const int tid  = threadIdx.x;
  const int lane = tid & 63;
  const int wave = tid >> 6;

  // ---- stage full channel codebook into LDS, quad-xor swizzle -------------
  const float4* cb4 = (const float4*)(cb + (size_t)c * 32768);
  float4* lds4 = (float4*)cb_lds;
#pragma unroll
  for (int i = 0; i < 16; ++i) {
    int idx = i * 512 + tid;            // float4 index 0..8191
    int k = idx >> 3, q = idx & 7;
    lds4[(k << 3) + (q ^ (k & 7))] = cb4[idx];
  }
  for (int i = tid; i < 1024; i += 512) qsum[i] = 0.f;
  __syncthreads();

  const float* cbsqp = ws_f + WS_CBSQ + c * 1024;
  float* out_q   = out + OUT_Q;
  float* out_idx = out + OUT_IDX;

  float accA0 = 0.f, accA1 = 0.f, accA2 = 0.f;
  float qb[16];
#pragma unroll
  for (int jj = 0; jj < 16; ++jj) qb[jj] = 0.f;
  const int kl7 = lane & 7;

#pragma unroll 1
  for (int p = 0; p < 16; ++p) {        // each wave: 16 n, one at a time
    const int n  = nblk * 128 + wave * 16 + p;
    const int b  = n >> 10;
    const int hw = n & 1023;
    const float* zp = z + (((size_t)b * 256 + c * 32) << 10) + hw;

    // wave-uniform z loads -> compiler scalarizes into SGPRs
    float zv[32];
#pragma unroll
    for (int d = 0; d < 32; ++d) zv[d] = zp[d * 1024];
    float zs = 0.f;
#pragma unroll
    for (int d = 0; d < 32; ++d) zs = fmaf(zv[d], zv[d], zs);

    float e[16];
    float zq[32];
#pragma unroll
    for (int d = 0; d < 32; ++d) zq[d] = 0.f;
    float S = 0.f, es = 0.f;
    float sm = -INFINITY;
    int km = 0;

#pragma unroll
    for (int jj = 0; jj < 16; ++jj) {   // k = jj*64 + lane, covers K=1024
      const int k = jj * 64 + lane;
      float cq = cbsqp[k];
      float row[32];
#pragma unroll
      for (int q = 0; q < 8; ++q) {
        float4 r4 = lds4[(k << 3) + (q ^ kl7)];
        row[q * 4 + 0] = r4.x; row[q * 4 + 1] = r4.y;
        row[q * 4 + 2] = r4.z; row[q * 4 + 3] = r4.w;
      }
      float c0 = 0.f, c1 = 0.f;
#pragma unroll
      for (int d = 0; d < 32; d += 2) {
        c0 = fmaf(row[d],     zv[d],     c0);
        c1 = fmaf(row[d + 1], zv[d + 1], c1);
      }
      float s = (c0 + c1) - 0.5f * cq;  // logits + const(n); dist = zs - 2s
      float ev = __expf(s);
      e[jj] = ev;
      S += ev;
      es = fmaf(ev, s, es);
      if (s > sm) { sm = s; km = k; }
#pragma unroll
      for (int d = 0; d < 32; ++d) zq[d] = fmaf(ev, row[d], zq[d]);
    }

    float St = wsum64(S);
    float rS = 1.f / St;
    float est = wsum64(es);

    // ---- pass 2: normalized q writes + q_bar (register-accumulated) -------
    float* qp = out_q + ((size_t)n * 8 + c) * 1024;
#pragma unroll
    for (int jj = 0; jj < 16; ++jj) {
      float qv = e[jj] * rS;
      __builtin_nontemporal_store(qv, qp + jj * 64 + lane);
      qb[jj] += qv;
    }

    accA1 += zs - 2.f * est * rS;              // E_dist(n)
    accA2 += est * rS - __logf(St);            // neg_ent(n) = es/S - log S

    // ---- argmax(s) == argmin(dist), tie -> lower k -------------------------
#pragma unroll
    for (int m = 32; m >= 1; m >>= 1) {
      float so = __shfl_xor(sm, m, 64); int ko = __shfl_xor(km, m, 64);
      if (so > sm || (so == sm && ko < km)) { sm = so; km = ko; }
    }
    if (lane == 0) {
      out_idx[(size_t)b * 8192 + c * 1024 + hw] = (float)km;
      ws_i[WS_IDX + n * 8 + c] = km;
    }

    // ---- split-butterfly reduce zq over 64 lanes; lane -> dd=(lane>>1)&31 --
#pragma unroll
    for (int t = 0; t < 5; ++t) {
      const int half = 16 >> t;
      const int up = (lane >> (5 - t)) & 1;
#pragma unroll
      for (int i = 0; i < half; ++i) {
        float sa = up ? zq[i] : zq[i + half];
        float ka = up ? zq[i + half] : zq[i];
        zq[i] = ka + __shfl_xor(sa, 32 >> t, 64);
      }
    }
    zq[0] += __shfl_xor(zq[0], 1, 64);
    const int ddl = (lane >> 1) & 31;
    float zf = zp[ddl * 1024];
    float d0 = zf - zq[0] * rS;
    accA0 += 0.5f * wsum64(d0 * d0);  // each dd counted twice across lanes
  }

  if (lane == 0) {
    atomicAdd(&ws_f[WS_A0], accA0);
    atomicAdd(&ws_f[WS_A1], accA1);
    atomicAdd(&ws_f[WS_A2], accA2);
  }

  // ---- q_bar: registers -> LDS (one atomic pass) -> global ----------------
#pragma unroll
  for (int jj = 0; jj < 16; ++jj)
    atomicAdd(&qsum[jj * 64 + lane], qb[jj]);
  __syncthreads();
  for (int k = tid; k < 1024; k += 512)
    atomicAdd(&ws_f[WS_QBAR + c * 1024 + k], qsum[k]);
}

// hard-quantized gather: coalesced writes of cb[c, idx[n,c], dd]
__global__ __launch_bounds__(256) void k_hard(const float* __restrict__ cb,
                                              const int* __restrict__ ws_i,
                                              float* __restrict__ out0) {
  int o = blockIdx.x * 256 + threadIdx.x;    // (b, ch, hw) row-major
  int b  = o >> 18;
  int r  = o & 262143;
  int ch = r >> 10;
  int hw = r & 1023;
  int c = ch >> 5, dd = ch & 31;
  int n = (b << 10) + hw;
  int k = ws_i[WS_IDX + n * 8 + c];
  out0[o] = cb[((size_t)(c << 10) + k) * 32 + dd];
}

__global__ __launch_bounds__(256) void k_final(const float* __restrict__ ws_f,
                                               float* __restrict__ out_s) {
  __shared__ float red[256];
  int tid = threadIdx.x;
  float bal = 0.f;
  for (int i = tid; i < 8192; i += 256) {
    float qb = ws_f[WS_QBAR + i] * (1.0f / 4096.0f);
    bal += qb * __logf(qb * 1024.0f + 1e-8f);
  }
  red[tid] = bal;
  __syncthreads();
  for (int s = 128; s > 0; s >>= 1) {
    if (tid < s) red[tid] += red[tid + s];
    __syncthreads();
  }
  if (tid == 0) {
    float A0 = ws_f[WS_A0], A1 = ws_f[WS_A1], A2 = ws_f[WS_A2];
    out_s[0] = A0 * (1.0f / 1048576.0f);                              // commitment
    out_s[1] = (0.5f * A1 + A2) * (1.0f / 32768.0f) + 6.93147180559945f; // free_energy
    out_s[2] = -A2 * (1.0f / 32768.0f);                               // confidence
    out_s[3] = red[0] * 0.125f;                                       // balance
    out_s[4] = 1.0f;                                                  // tau
  }
}

extern "C" void kernel_launch(void* const* d_in, const int* in_sizes, int n_in,
                              void* d_out, int out_size, void* d_ws, size_t ws_size,
                              hipStream_t stream) {
  (void)in_sizes; (void)n_in; (void)out_size; (void)ws_size;
  const float* z  = (const float*)d_in[0];
  const float* cb = (const float*)d_in[1];
  float* out  = (float*)d_out;
  float* ws_f = (float*)d_ws;
  int*   ws_i = (int*)d_ws;

  // 132KB dynamic LDS (> 64KB default): opt in every call (idempotent, cheap)
  hipFuncSetAttribute(reinterpret_cast<const void*>(k_main),
                      hipFuncAttributeMaxDynamicSharedMemorySize, 135168);

  hipMemsetAsync(d_ws, 0, (WS_QBAR + 8192) * sizeof(float), stream);
  k_cbsq <<<32,   256, 0,      stream>>>(cb, ws_f);
  k_main <<<256,  512, 135168, stream>>>(z, cb, out, ws_f, ws_i);
  k_hard <<<4096, 256, 0,      stream>>>(cb, ws_i, out);
  k_final<<<1,    256, 0,      stream>>>(ws_f, out + OUT_SCAL);
}

// Round 3
// 2032.535 us; speedup vs baseline: 1.3862x; 1.0219x over previous
//
#include <hip/hip_runtime.h>

// ---------------- workspace layout (float/int indices into d_ws) ----------
#define WS_A0 0              // commitment sum
#define WS_A1 1              // sum of E_dist over (n,c)
#define WS_A2 2              // sum of neg_ent over (n,c)
#define WS_QBAR 16           // 8192 floats: sum_n q[n,c,k]
#define WS_CBSQ (WS_QBAR + 8192)   // 8192 floats: ||cb[c,k]||^2
#define WS_IDX  (WS_CBSQ + 8192)   // 32768 ints: argmin index per (n,c)

// ---------------- output layout (floats) ----------------------------------
#define OUT_IDX  1048576     // indices (B,C,H,W) as float
#define OUT_Q    1081344     // q (N,C,K)
#define OUT_SCAL 34635776    // commitment, free_energy, confidence, balance, tau

__global__ __launch_bounds__(256) void k_cbsq(const float* __restrict__ cb,
                                              float* __restrict__ ws_f) {
  int i = blockIdx.x * 256 + threadIdx.x;   // 0..8191  (= c*1024 + k)
  const float* r = cb + (size_t)i * 32;
  float s = 0.f;
#pragma unroll
  for (int d = 0; d < 32; ++d) s = fmaf(r[d], r[d], s);
  ws_f[WS_CBSQ + i] = s;
}

__device__ __forceinline__ float wsum64(float v) {
#pragma unroll
  for (int m = 32; m >= 1; m >>= 1) v += __shfl_xor(v, m, 64);
  return v;
}

__device__ __forceinline__ float uread(float v) {
  // wave-uniform value -> SGPR (exact; all lanes hold the same bits)
  return __int_as_float(__builtin_amdgcn_readfirstlane(__float_as_int(v)));
}

// main: 256 blocks (8 c x 32 n-blocks), 512 threads (8 waves), 132KB dyn LDS.
// 132KB LDS => 1 block/CU = 8 waves = 2 waves/EU. amdgpu_waves_per_eu(2,2)
// pins the allocator's occupancy target there -> 256-VGPR budget. R1/R2's
// launch_bounds 2nd arg was ignored (VGPR stuck at 128 -> 3.9GB spill reads).
__global__ __launch_bounds__(512)
__attribute__((amdgpu_waves_per_eu(2, 2)))
void k_main(
    const float* __restrict__ z, const float* __restrict__ cb,
    float* __restrict__ out, float* __restrict__ ws_f, int* __restrict__ ws_i) {
  extern __shared__ float smem[];
  float* cb_lds = smem;            // 32768 floats, xor-swizzled float4 quads
  float* qsum   = smem + 32768;    // 1024 floats: per-block sum_n q

  const int c    = blockIdx.x >> 5;
  const int nblk = blockIdx.x & 31;
  const int tid  = threadIdx.x;
  const int lane = tid & 63;
  const int wave = tid >> 6;

  // ---- stage full channel codebook into LDS, quad-xor swizzle -------------
  const float4* cb4 = (const float4*)(cb + (size_t)c * 32768);
  float4* lds4 = (float4*)cb_lds;
#pragma unroll
  for (int i = 0; i < 16; ++i) {
    int idx = i * 512 + tid;            // float4 index 0..8191
    int k = idx >> 3, q = idx & 7;
    lds4[(k << 3) + (q ^ (k & 7))] = cb4[idx];
  }
  for (int i = tid; i < 1024; i += 512) qsum[i] = 0.f;
  __syncthreads();

  const float* cbsqp = ws_f + WS_CBSQ + c * 1024;
  float* out_q   = out + OUT_Q;
  float* out_idx = out + OUT_IDX;

  float accA0 = 0.f, accA1 = 0.f, accA2 = 0.f;
  float qb[16];
#pragma unroll
  for (int jj = 0; jj < 16; ++jj) qb[jj] = 0.f;
  const int kl7 = lane & 7;

#pragma unroll 1
  for (int p = 0; p < 16; ++p) {        // each wave: 16 n, one at a time
    const int n  = nblk * 128 + wave * 16 + p;
    const int b  = n >> 10;
    const int hw = n & 1023;
    const float* zp = z + (((size_t)b * 256 + c * 32) << 10) + hw;

    // wave-uniform z -> force into SGPRs (frees 32 VGPRs)
    float zv[32];
#pragma unroll
    for (int d = 0; d < 32; ++d) zv[d] = uread(zp[d * 1024]);
    float zs = 0.f;
#pragma unroll
    for (int d = 0; d < 32; ++d) zs = fmaf(zv[d], zv[d], zs);

    float e[16];
    float zq[32];
#pragma unroll
    for (int d = 0; d < 32; ++d) zq[d] = 0.f;
    float S = 0.f, es = 0.f;
    float sm = -INFINITY;
    int km = 0;

#pragma unroll
    for (int jj = 0; jj < 16; ++jj) {   // k = jj*64 + lane, covers K=1024
      const int k = jj * 64 + lane;
      float cq = cbsqp[k];
      float row[32];
#pragma unroll
      for (int q = 0; q < 8; ++q) {
        float4 r4 = lds4[(k << 3) + (q ^ kl7)];
        row[q * 4 + 0] = r4.x; row[q * 4 + 1] = r4.y;
        row[q * 4 + 2] = r4.z; row[q * 4 + 3] = r4.w;
      }
      float c0 = 0.f, c1 = 0.f;
#pragma unroll
      for (int d = 0; d < 32; d += 2) {
        c0 = fmaf(row[d],     zv[d],     c0);
        c1 = fmaf(row[d + 1], zv[d + 1], c1);
      }
      float s = (c0 + c1) - 0.5f * cq;  // logits + const(n); dist = zs - 2s
      float ev = __expf(s);
      e[jj] = ev;
      S += ev;
      es = fmaf(ev, s, es);
      if (s > sm) { sm = s; km = k; }
#pragma unroll
      for (int d = 0; d < 32; ++d) zq[d] = fmaf(ev, row[d], zq[d]);
    }

    float St = wsum64(S);
    float rS = 1.f / St;
    float est = wsum64(es);

    // ---- pass 2: normalized q writes + q_bar (register-accumulated) -------
    float* qp = out_q + ((size_t)n * 8 + c) * 1024;
#pragma unroll
    for (int jj = 0; jj < 16; ++jj) {
      float qv = e[jj] * rS;
      __builtin_nontemporal_store(qv, qp + jj * 64 + lane);
      qb[jj] += qv;
    }

    accA1 += zs - 2.f * est * rS;              // E_dist(n)
    accA2 += est * rS - __logf(St);            // neg_ent(n) = es/S - log S

    // ---- argmax(s) == argmin(dist), tie -> lower k -------------------------
#pragma unroll
    for (int m = 32; m >= 1; m >>= 1) {
      float so = __shfl_xor(sm, m, 64); int ko = __shfl_xor(km, m, 64);
      if (so > sm || (so == sm && ko < km)) { sm = so; km = ko; }
    }
    if (lane == 0) {
      out_idx[(size_t)b * 8192 + c * 1024 + hw] = (float)km;
      ws_i[WS_IDX + n * 8 + c] = km;
    }

    // ---- split-butterfly reduce zq over 64 lanes; lane -> dd=(lane>>1)&31 --
#pragma unroll
    for (int t = 0; t < 5; ++t) {
      const int half = 16 >> t;
      const int up = (lane >> (5 - t)) & 1;
#pragma unroll
      for (int i = 0; i < half; ++i) {
        float sa = up ? zq[i] : zq[i + half];
        float ka = up ? zq[i + half] : zq[i];
        zq[i] = ka + __shfl_xor(sa, 32 >> t, 64);
      }
    }
    zq[0] += __shfl_xor(zq[0], 1, 64);
    const int ddl = (lane >> 1) & 31;
    float zf = zp[ddl * 1024];
    float d0 = zf - zq[0] * rS;
    accA0 += 0.5f * wsum64(d0 * d0);  // each dd counted twice across lanes
  }

  if (lane == 0) {
    atomicAdd(&ws_f[WS_A0], accA0);
    atomicAdd(&ws_f[WS_A1], accA1);
    atomicAdd(&ws_f[WS_A2], accA2);
  }

  // ---- q_bar: registers -> LDS (one atomic pass) -> global ----------------
#pragma unroll
  for (int jj = 0; jj < 16; ++jj)
    atomicAdd(&qsum[jj * 64 + lane], qb[jj]);
  __syncthreads();
  for (int k = tid; k < 1024; k += 512)
    atomicAdd(&ws_f[WS_QBAR + c * 1024 + k], qsum[k]);
}

// hard-quantized gather: coalesced writes of cb[c, idx[n,c], dd]
__global__ __launch_bounds__(256) void k_hard(const float* __restrict__ cb,
                                              const int* __restrict__ ws_i,
                                              float* __restrict__ out0) {
  int o = blockIdx.x * 256 + threadIdx.x;    // (b, ch, hw) row-major
  int b  = o >> 18;
  int r  = o & 262143;
  int ch = r >> 10;
  int hw = r & 1023;
  int c = ch >> 5, dd = ch & 31;
  int n = (b << 10) + hw;
  int k = ws_i[WS_IDX + n * 8 + c];
  out0[o] = cb[((size_t)(c << 10) + k) * 32 + dd];
}

__global__ __launch_bounds__(256) void k_final(const float* __restrict__ ws_f,
                                               float* __restrict__ out_s) {
  __shared__ float red[256];
  int tid = threadIdx.x;
  float bal = 0.f;
  for (int i = tid; i < 8192; i += 256) {
    float qb = ws_f[WS_QBAR + i] * (1.0f / 4096.0f);
    bal += qb * __logf(qb * 1024.0f + 1e-8f);
  }
  red[tid] = bal;
  __syncthreads();
  for (int s = 128; s > 0; s >>= 1) {
    if (tid < s) red[tid] += red[tid + s];
    __syncthreads();
  }
  if (tid == 0) {
    float A0 = ws_f[WS_A0], A1 = ws_f[WS_A1], A2 = ws_f[WS_A2];
    out_s[0] = A0 * (1.0f / 1048576.0f);                              // commitment
    out_s[1] = (0.5f * A1 + A2) * (1.0f / 32768.0f) + 6.93147180559945f; // free_energy
    out_s[2] = -A2 * (1.0f / 32768.0f);                               // confidence
    out_s[3] = red[0] * 0.125f;                                       // balance
    out_s[4] = 1.0f;                                                  // tau
  }
}

extern "C" void kernel_launch(void* const* d_in, const int* in_sizes, int n_in,
                              void* d_out, int out_size, void* d_ws, size_t ws_size,
                              hipStream_t stream) {
  (void)in_sizes; (void)n_in; (void)out_size; (void)ws_size;
  const float* z  = (const float*)d_in[0];
  const float* cb = (const float*)d_in[1];
  float* out  = (float*)d_out;
  float* ws_f = (float*)d_ws;
  int*   ws_i = (int*)d_ws;

  // 132KB dynamic LDS (> 64KB default): opt in every call (idempotent, cheap)
  hipFuncSetAttribute(reinterpret_cast<const void*>(k_main),
                      hipFuncAttributeMaxDynamicSharedMemorySize, 135168);

  hipMemsetAsync(d_ws, 0, (WS_QBAR + 8192) * sizeof(float), stream);
  k_cbsq <<<32,   256, 0,      stream>>>(cb, ws_f);
  k_main <<<256,  512, 135168, stream>>>(z, cb, out, ws_f, ws_i);
  k_hard <<<4096, 256, 0,      stream>>>(cb, ws_i, out);
  k_final<<<1,    256, 0,      stream>>>(ws_f, out + OUT_SCAL);
}